// Round 9
// baseline (4447.426 us; speedup 1.0000x reference)
//
#include <hip/hip_runtime.h>
#include <hip/hip_fp8.h>

typedef unsigned short u16;
typedef unsigned char u8;
typedef unsigned int u32;
typedef long long i64;
typedef __attribute__((ext_vector_type(8))) short short8;
typedef __attribute__((ext_vector_type(4))) float f32x4;

constexpr int HD = 2048;     // hidden / K (bytes in fp8)
constexpr int NR = 4096;     // rows B*S
constexpr int VO = 128000;   // vocab

// ---------------- fp8 path geometry: 256^2 tile, K-tile = 64 B ----------------
constexpr int NMB8 = NR / 256;    // 16
constexpr int NVB8 = VO / 256;    // 500
constexpr int NT8  = HD / 64;     // 32 K-tiles
constexpr float XSCALE = 32.0f;
constexpr float WSCALE = 16384.0f;
constexpr float UNSCALE = 1.0f / (XSCALE * WSCALE);

// ws layout (fp8 path)
constexpr size_t OFF_X8  = 0;                          // 8,388,608
constexpr size_t OFF_W8  = 8388608;                    // 262,144,000
constexpr size_t OFF_PMX = OFF_W8 + 262144000;         // 8,192,000
constexpr size_t OFF_PSM = OFF_PMX + 8192000;
constexpr size_t OFF_LSE = OFF_PSM + 8192000;
constexpr size_t OFF_TL  = OFF_LSE + 16384;
constexpr size_t NEED_NEW = OFF_TL + 16384;            // ~287 MB

// ws layout, fallback (round-1 bf16 128^2, proven)
constexpr int NVBF = VO / 128;
constexpr int NMBF = NR / 128;
constexpr size_t FB_XB   = 0;
constexpr size_t FB_PMAX = 16777216;
constexpr size_t FB_PSUM = FB_PMAX + 16384000;
constexpr size_t FB_LSE  = FB_PSUM + 16384000;
constexpr size_t FB_TL   = FB_LSE + (size_t)NR * 4;

// fallback swizzle
__device__ __forceinline__ u32 swz16(u32 a) { return a ^ (((a >> 7) & 3u) << 4); }

__device__ __forceinline__ u8 f2e4m3(float f) {
  return (u8)__hip_cvt_float_to_fp8(f, __HIP_SATFINITE, __HIP_E4M3);
}

// ---------------- x f32 -> fp8, kk-interleaved layout ----------------
// Global layout per row, per 64B K-block: byte (q*16 + kk*8 + b) holds
// logical element k = kk*32 + q*8 + b. So each lane's 16B LDS cell (q-slot)
// contains BOTH kk halves of its MFMA operand -> single ds_read_b128.
__global__ __launch_bounds__(256) void cvt_x8_kernel(const float* __restrict__ x,
                                                     u8* __restrict__ x8) {
  const long c = (long)blockIdx.x * 256 + threadIdx.x;   // 16B cell index
  const long row = c >> 7;                                // HD/16 = 128 cells/row
  const int ci = (int)(c & 127);
  const int tb = ci >> 2, q = ci & 3;
  const float* base = x + row * HD + tb * 64 + q * 8;
  float4 a0 = *reinterpret_cast<const float4*>(base);
  float4 a1 = *reinterpret_cast<const float4*>(base + 4);
  float4 a2 = *reinterpret_cast<const float4*>(base + 32);
  float4 a3 = *reinterpret_cast<const float4*>(base + 36);
  union { u8 b[16]; uint4 v; } p;
  p.b[0] = f2e4m3(a0.x * XSCALE); p.b[1] = f2e4m3(a0.y * XSCALE);
  p.b[2] = f2e4m3(a0.z * XSCALE); p.b[3] = f2e4m3(a0.w * XSCALE);
  p.b[4] = f2e4m3(a1.x * XSCALE); p.b[5] = f2e4m3(a1.y * XSCALE);
  p.b[6] = f2e4m3(a1.z * XSCALE); p.b[7] = f2e4m3(a1.w * XSCALE);
  p.b[8]  = f2e4m3(a2.x * WSCALE * 0 + a2.x * XSCALE); // keep simple below
  p.b[8]  = f2e4m3(a2.x * XSCALE); p.b[9]  = f2e4m3(a2.y * XSCALE);
  p.b[10] = f2e4m3(a2.z * XSCALE); p.b[11] = f2e4m3(a2.w * XSCALE);
  p.b[12] = f2e4m3(a3.x * XSCALE); p.b[13] = f2e4m3(a3.y * XSCALE);
  p.b[14] = f2e4m3(a3.z * XSCALE); p.b[15] = f2e4m3(a3.w * XSCALE);
  reinterpret_cast<uint4*>(x8)[c] = p.v;
}

// ---------------- W f32 -> fp8, same kk-interleaved layout ----------------
__global__ __launch_bounds__(256) void cvt_w8_kernel(const float* __restrict__ W,
                                                     u8* __restrict__ w8) {
  const long total = (long)VO * HD / 16;                 // cells
  long c = (long)blockIdx.x * 256 + threadIdx.x;
  const long stride = (long)gridDim.x * 256;
  for (; c < total; c += stride) {
    const long row = c >> 7;
    const int ci = (int)(c & 127);
    const int tb = ci >> 2, q = ci & 3;
    const float* base = W + row * HD + tb * 64 + q * 8;
    float4 a0 = *reinterpret_cast<const float4*>(base);
    float4 a1 = *reinterpret_cast<const float4*>(base + 4);
    float4 a2 = *reinterpret_cast<const float4*>(base + 32);
    float4 a3 = *reinterpret_cast<const float4*>(base + 36);
    union { u8 b[16]; uint4 v; } p;
    p.b[0] = f2e4m3(a0.x * WSCALE); p.b[1] = f2e4m3(a0.y * WSCALE);
    p.b[2] = f2e4m3(a0.z * WSCALE); p.b[3] = f2e4m3(a0.w * WSCALE);
    p.b[4] = f2e4m3(a1.x * WSCALE); p.b[5] = f2e4m3(a1.y * WSCALE);
    p.b[6] = f2e4m3(a1.z * WSCALE); p.b[7] = f2e4m3(a1.w * WSCALE);
    p.b[8]  = f2e4m3(a2.x * WSCALE); p.b[9]  = f2e4m3(a2.y * WSCALE);
    p.b[10] = f2e4m3(a2.z * WSCALE); p.b[11] = f2e4m3(a2.w * WSCALE);
    p.b[12] = f2e4m3(a3.x * WSCALE); p.b[13] = f2e4m3(a3.y * WSCALE);
    p.b[14] = f2e4m3(a3.z * WSCALE); p.b[15] = f2e4m3(a3.w * WSCALE);
    reinterpret_cast<uint4*>(w8)[c] = p.v;
  }
}

// ============ 16-wave 256^2 fp8 fused GEMM + softmax partials ============
// Triple-buffered LDS + REGISTER-double-buffered fragments:
// body(T): stage T+2 -> vmcnt(2)+BAR (T+1 landed; T-1 readers retired a full
// body ago) -> ds_read frags(T+1) [b128, conflict-free slot-XOR layout]
// in parallel with MFMA on frags(T) (no dependency) -> lgkm0+sched_barrier.
// LDS slot-XOR: cell at (row, s_st) holds logical slot q = s_st ^ (row&3);
// fragment read addr slot = q ^ (r15&3) -> 8 lanes per 4-bank group = b128
// minimum, conflict-free. Staging source: row*HD + t*64 + (s_st^(row&3))*16.
__global__ __launch_bounds__(1024, 4) void gemm8(
    const u8* __restrict__ x8, const u8* __restrict__ w8,
    float* __restrict__ pmax, float* __restrict__ psum) {
  __shared__ uint4 smem4[6144];                 // 96 KB: 3 bufs x {A 16K, B 16K}
  __shared__ float smax[256][4];
  __shared__ float ssum[256][4];
  char* Sm = reinterpret_cast<char*>(smem4);

  const int tid = threadIdx.x;
  const int w = tid >> 6, l = tid & 63;
  const int wr = w >> 2, wc = w & 3;            // 4M x 4N waves, 64x64 each
  const int q = l >> 4, r15 = l & 15;

  // XCD-bijective swizzle: 8000 = 8 * 1000; mb fast (W panel L2-reuse)
  const int bid = blockIdx.x;
  const int s = (bid & 7) * 1000 + (bid >> 3);
  const int mb = s & (NMB8 - 1);
  const int vb = s >> 4;
  const int rowbase = mb * 256, vbase = vb * 256;

  // -------- staging: linear LDS dest; source picks logical slot ----------
  const u32 lin = (u32)tid * 16u;
  const u32 srow = lin >> 6;                    // 0..255
  const u32 s_st = (lin >> 4) & 3u;             // stored slot
  const u32 qsl = s_st ^ (srow & 3u);           // logical slot
  const u8* aRp = x8 + (size_t)(rowbase + (int)srow) * HD + qsl * 16u;
  const u8* bRp = w8 + (size_t)(vbase + (int)srow) * HD + qsl * 16u;
  const u32 aDstB = (u32)(w * 1024);            // + bufOff
  const u32 bDstB = (u32)(16384 + w * 1024);    // + bufOff

  auto stg = [&](const u8* src, u32 dstOff) {
    __builtin_amdgcn_global_load_lds(
        (const __attribute__((address_space(1))) u32*)src,
        (__attribute__((address_space(3))) u32*)(Sm + dstOff), 16, 0, 0);
  };

  // -------- fragment read addrs: one b128 per (jj)/(nn), slot = q^(r15&3) ----
  const u32 slot = ((u32)q ^ ((u32)r15 & 3u)) << 4;
  u32 aA[4], bA[4];
#pragma unroll
  for (int jj = 0; jj < 4; ++jj)
    aA[jj] = ((u32)(wr * 64 + jj * 16 + r15) << 6) + slot;
#pragma unroll
  for (int nn = 0; nn < 4; ++nn)
    bA[nn] = 16384u + ((u32)(wc * 64 + nn * 16 + r15) << 6) + slot;

  union U4 { uint4 v; i64 d[2]; };
  U4 fa0[4], fb0[4], fa1[4], fb1[4];
  f32x4 acc[4][4];
#pragma unroll
  for (int m = 0; m < 4; ++m)
#pragma unroll
    for (int n = 0; n < 4; ++n) acc[m][n] = (f32x4)(0.0f);

  // -------- prologue: stage T0 -> buf0, T1 -> buf1; preload frags(T0) --------
  stg(aRp, aDstB);
  stg(bRp, bDstB);
  stg(aRp + 64, aDstB + 32768u);
  stg(bRp + 64, bDstB + 32768u);
  asm volatile("s_waitcnt vmcnt(2)" ::: "memory");
  __builtin_amdgcn_s_barrier();
#pragma unroll
  for (int jj = 0; jj < 4; ++jj) fa0[jj].v = *reinterpret_cast<const uint4*>(Sm + aA[jj]);
#pragma unroll
  for (int nn = 0; nn < 4; ++nn) fb0[nn].v = *reinterpret_cast<const uint4*>(Sm + bA[nn]);

  u32 rdOff = 32768u;                           // frags(T1) from buf1
  u32 stOff = 65536u;                           // T2 -> buf2

  auto tileBody = [&](U4 (&fM)[4], U4 (&gM)[4], U4 (&fL)[4], U4 (&gL)[4], int t) {
    if (t + 2 < NT8) {
      stg(aRp + (size_t)(t + 2) * 64, aDstB + stOff);
      stg(bRp + (size_t)(t + 2) * 64, bDstB + stOff);
    }
    if (t + 1 < NT8) {
      if (t + 2 < NT8) asm volatile("s_waitcnt vmcnt(2)" ::: "memory");
      else             asm volatile("s_waitcnt vmcnt(0)" ::: "memory");
      __builtin_amdgcn_s_barrier();             // tile T+1 landed everywhere
#pragma unroll
      for (int jj = 0; jj < 4; ++jj) fL[jj].v = *reinterpret_cast<const uint4*>(Sm + rdOff + aA[jj]);
#pragma unroll
      for (int nn = 0; nn < 4; ++nn) gL[nn].v = *reinterpret_cast<const uint4*>(Sm + rdOff + bA[nn]);
    }
    // MFMA on frags(T) — independent of the loads above -> pipes overlap
    __builtin_amdgcn_s_setprio(1);
#pragma unroll
    for (int jj = 0; jj < 4; ++jj)
#pragma unroll
      for (int nn = 0; nn < 4; ++nn) {
        acc[jj][nn] = __builtin_amdgcn_mfma_f32_16x16x32_fp8_fp8(
            fM[jj].d[0], gM[nn].d[0], acc[jj][nn], 0, 0, 0);
        acc[jj][nn] = __builtin_amdgcn_mfma_f32_16x16x32_fp8_fp8(
            fM[jj].d[1], gM[nn].d[1], acc[jj][nn], 0, 0, 0);
      }
    __builtin_amdgcn_s_setprio(0);
    // pin: this wave's ds_reads retired before it can pass the next barrier
    asm volatile("s_waitcnt lgkmcnt(0)" ::: "memory");
    __builtin_amdgcn_sched_barrier(0);
    rdOff = (rdOff == 65536u) ? 0u : rdOff + 32768u;
    stOff = (stOff == 65536u) ? 0u : stOff + 32768u;
  };

  for (int t = 0; t < NT8; t += 2) {
    tileBody(fa0, fb0, fa1, fb1, t);
    tileBody(fa1, fb1, fa0, fb0, t + 1);
  }

  // -------- epilogue: unscale, per-row max + sum(exp) over 256 vocab cols ----
  // C/D: col = lane&15, row = (lane>>4)*4 + reg. Wave rows: wr*64+jj*16+q*4+j;
  // wave cols: wc*64 + nn*16 + (lane&15).
#pragma unroll
  for (int jj = 0; jj < 4; ++jj) {
#pragma unroll
    for (int j = 0; j < 4; ++j) {
      float v0 = acc[jj][0][j] * UNSCALE, v1 = acc[jj][1][j] * UNSCALE;
      float v2 = acc[jj][2][j] * UNSCALE, v3 = acc[jj][3][j] * UNSCALE;
      float mx = fmaxf(fmaxf(v0, v1), fmaxf(v2, v3));
#pragma unroll
      for (int d = 1; d < 16; d <<= 1) mx = fmaxf(mx, __shfl_xor(mx, d));
      float se = __expf(v0 - mx) + __expf(v1 - mx) + __expf(v2 - mx) + __expf(v3 - mx);
#pragma unroll
      for (int d = 1; d < 16; d <<= 1) se += __shfl_xor(se, d);
      if (r15 == 0) {
        int r = wr * 64 + jj * 16 + q * 4 + j;
        smax[r][wc] = mx;
        ssum[r][wc] = se;
      }
    }
  }
  __syncthreads();
  if (tid < 256) {
    float m0 = smax[tid][0], m1 = smax[tid][1], m2 = smax[tid][2], m3 = smax[tid][3];
    float M = fmaxf(fmaxf(m0, m1), fmaxf(m2, m3));
    float S = ssum[tid][0] * __expf(m0 - M) + ssum[tid][1] * __expf(m1 - M) +
              ssum[tid][2] * __expf(m2 - M) + ssum[tid][3] * __expf(m3 - M);
    size_t o = (size_t)vb * NR + (size_t)(rowbase + tid);
    pmax[o] = M;
    psum[o] = S;
  }
}

// ================= fallback path (round-1 bf16, proven) =================
__global__ __launch_bounds__(256) void cvt_x_kernel(const float* __restrict__ x,
                                                    u16* __restrict__ xb) {
  int i = blockIdx.x * 256 + threadIdx.x;
  float4 v = reinterpret_cast<const float4*>(x)[i];
  union { __bf16 b[4]; unsigned long long ll; } p;
  p.b[0] = (__bf16)v.x; p.b[1] = (__bf16)v.y;
  p.b[2] = (__bf16)v.z; p.b[3] = (__bf16)v.w;
  reinterpret_cast<unsigned long long*>(xb)[i] = p.ll;
}

__global__ __launch_bounds__(256) void gemm_partials_fb(
    const u16* __restrict__ xb, const float* __restrict__ W,
    float* __restrict__ pmax, float* __restrict__ psum) {
  __shared__ uint4 smem[1024];
  __shared__ float smax[128][2];
  __shared__ float ssum[128][2];
  char* Ab = reinterpret_cast<char*>(smem);
  char* Bb = Ab + 8192;

  const int tid = threadIdx.x;
  const int w = tid >> 6;
  const int l = tid & 63;
  const int wr = w >> 1, wc = w & 1;

  const int bid = blockIdx.x;
  const int s = (bid & 7) * (NMBF * NVBF / 8) + (bid >> 3);
  const int mb = s & (NMBF - 1);
  const int vb = s >> 5;
  const int rowbase = mb * 128;
  const int vbase = vb * 128;

  const u16* aSrc[2];
  unsigned aBase[2];
#pragma unroll
  for (int i = 0; i < 2; ++i) {
    unsigned lin = (unsigned)w * 2048u + (unsigned)i * 1024u + (unsigned)l * 16u;
    unsigned sb = swz16(lin);
    unsigned r = sb >> 6;
    unsigned c = (sb >> 1) & 31u;
    aSrc[i] = xb + (size_t)(rowbase + (int)r) * HD + c;
    aBase[i] = (unsigned)w * 2048u + (unsigned)i * 1024u;
  }
  const float* bSrc[2];
  unsigned bLin[2];
#pragma unroll
  for (int i = 0; i < 2; ++i) {
    unsigned lin = (unsigned)i * 4096u + (unsigned)tid * 16u;
    unsigned sb = swz16(lin);
    unsigned n = sb >> 6;
    unsigned k = (sb >> 1) & 31u;
    bSrc[i] = W + (size_t)(vbase + (int)n) * HD + k;
    bLin[i] = lin;
  }
  const unsigned q = (unsigned)(l >> 4);
  unsigned aOff[4], bOff[4];
#pragma unroll
  for (int m = 0; m < 4; ++m) {
    unsigned R = (unsigned)(wr * 64 + m * 16 + (l & 15));
    aOff[m] = swz16(R * 64u + q * 16u);
    R = (unsigned)(wc * 64 + m * 16 + (l & 15));
    bOff[m] = swz16(R * 64u + q * 16u);
  }
  f32x4 acc[4][4];
#pragma unroll
  for (int m = 0; m < 4; ++m)
#pragma unroll
    for (int n = 0; n < 4; ++n) acc[m][n] = (f32x4)(0.0f);

  for (int kt = 0; kt < HD; kt += 32) {
    float4 g0 = *reinterpret_cast<const float4*>(bSrc[0]);
    float4 g1 = *reinterpret_cast<const float4*>(bSrc[0] + 4);
    float4 g2 = *reinterpret_cast<const float4*>(bSrc[1]);
    float4 g3 = *reinterpret_cast<const float4*>(bSrc[1] + 4);
#pragma unroll
    for (int i = 0; i < 2; ++i) {
      __builtin_amdgcn_global_load_lds(
          (const __attribute__((address_space(1))) u32*)aSrc[i],
          (__attribute__((address_space(3))) u32*)(Ab + aBase[i]), 16, 0, 0);
    }
    union { __bf16 b[8]; uint4 v; } p0, p1;
    p0.b[0] = (__bf16)g0.x; p0.b[1] = (__bf16)g0.y; p0.b[2] = (__bf16)g0.z; p0.b[3] = (__bf16)g0.w;
    p0.b[4] = (__bf16)g1.x; p0.b[5] = (__bf16)g1.y; p0.b[6] = (__bf16)g1.z; p0.b[7] = (__bf16)g1.w;
    p1.b[0] = (__bf16)g2.x; p1.b[1] = (__bf16)g2.y; p1.b[2] = (__bf16)g2.z; p1.b[3] = (__bf16)g2.w;
    p1.b[4] = (__bf16)g3.x; p1.b[5] = (__bf16)g3.y; p1.b[6] = (__bf16)g3.z; p1.b[7] = (__bf16)g3.w;
    *reinterpret_cast<uint4*>(Bb + bLin[0]) = p0.v;
    *reinterpret_cast<uint4*>(Bb + bLin[1]) = p1.v;
    __syncthreads();

    short8 af[4], bfr[4];
#pragma unroll
    for (int m = 0; m < 4; ++m) af[m] = *reinterpret_cast<const short8*>(Ab + aOff[m]);
#pragma unroll
    for (int n = 0; n < 4; ++n) bfr[n] = *reinterpret_cast<const short8*>(Bb + bOff[n]);
#pragma unroll
    for (int m = 0; m < 4; ++m)
#pragma unroll
      for (int n = 0; n < 4; ++n)
        acc[m][n] = __builtin_amdgcn_mfma_f32_16x16x32_bf16(af[m], bfr[n], acc[m][n], 0, 0, 0);
    __syncthreads();

    aSrc[0] += 32; aSrc[1] += 32;
    bSrc[0] += 32; bSrc[1] += 32;
  }
#pragma unroll
  for (int m = 0; m < 4; ++m) {
#pragma unroll
    for (int j = 0; j < 4; ++j) {
      float v0 = acc[m][0][j], v1 = acc[m][1][j], v2 = acc[m][2][j], v3 = acc[m][3][j];
      float mx = fmaxf(fmaxf(v0, v1), fmaxf(v2, v3));
#pragma unroll
      for (int d = 1; d < 16; d <<= 1) mx = fmaxf(mx, __shfl_xor(mx, d));
      float se = __expf(v0 - mx) + __expf(v1 - mx) + __expf(v2 - mx) + __expf(v3 - mx);
#pragma unroll
      for (int d = 1; d < 16; d <<= 1) se += __shfl_xor(se, d);
      if ((l & 15) == 0) {
        int rloc = wr * 64 + m * 16 + (int)q * 4 + j;
        smax[rloc][wc] = mx;
        ssum[rloc][wc] = se;
      }
    }
  }
  __syncthreads();
  if (tid < 128) {
    float m0 = smax[tid][0], m1 = smax[tid][1];
    float M = fmaxf(m0, m1);
    float S = ssum[tid][0] * __expf(m0 - M) + ssum[tid][1] * __expf(m1 - M);
    size_t o = (size_t)vb * NR + (size_t)(rowbase + tid);
    pmax[o] = M;
    psum[o] = S;
  }
}

// ---------------- merge partials -> LSE per row ----------------
__global__ __launch_bounds__(256) void row_lse_kernel(const float* __restrict__ pmax,
                                                      const float* __restrict__ psum,
                                                      float* __restrict__ lse, int nvb) {
  __shared__ float lm[4][64];
  __shared__ float ls[4][64];
  const int rb = blockIdx.x * 64;
  const int rl = threadIdx.x & 63;
  const int g = threadIdx.x >> 6;
  const int r = rb + rl;
  float M = -3.0e38f, S = 0.0f;
  for (int v = g; v < nvb; v += 4) {
    float m = pmax[(size_t)v * NR + r];
    float s = psum[(size_t)v * NR + r];
    float nM = fmaxf(M, m);
    S = S * __expf(M - nM) + s * __expf(m - nM);
    M = nM;
  }
  lm[g][rl] = M; ls[g][rl] = S;
  __syncthreads();
  if (threadIdx.x < 64) {
    float M0 = lm[0][rl], S0 = ls[0][rl];
#pragma unroll
    for (int g2 = 1; g2 < 4; ++g2) {
      float m = lm[g2][rl], s2 = ls[g2][rl];
      float nM = fmaxf(M0, m);
      S0 = S0 * __expf(M0 - nM) + s2 * __expf(m - nM);
      M0 = nM;
    }
    lse[r] = M0 + logf(S0);
  }
}

// ---------------- target logit: dot(x[n], W[y[n]]) in f32 (exact) ----------------
__global__ __launch_bounds__(256) void tlogit_kernel(const float* __restrict__ x,
                                                     const int* __restrict__ y,
                                                     const float* __restrict__ W,
                                                     float* __restrict__ tl) {
  const int row = blockIdx.x * 4 + (threadIdx.x >> 6);
  const int l = threadIdx.x & 63;
  const int t = y[row];
  const float4* xr = reinterpret_cast<const float4*>(x + (size_t)row * HD);
  const float4* wr = reinterpret_cast<const float4*>(W + (size_t)t * HD);
  float s = 0.0f;
#pragma unroll
  for (int i = 0; i < HD / 4 / 64; ++i) {
    float4 a = xr[l + i * 64];
    float4 b = wr[l + i * 64];
    s += a.x * b.x + a.y * b.y + a.z * b.z + a.w * b.w;
  }
#pragma unroll
  for (int d = 1; d < 64; d <<= 1) s += __shfl_xor(s, d);
  if (l == 0) tl[row] = s;
}

// ---------------- mean(lse - tlogit) ----------------
__global__ __launch_bounds__(256) void finalize_kernel(const float* __restrict__ lse,
                                                       const float* __restrict__ tl,
                                                       float* __restrict__ out) {
  __shared__ float red[256];
  float s = 0.0f;
  for (int i = threadIdx.x; i < NR; i += 256) s += lse[i] - tl[i];
  red[threadIdx.x] = s;
  __syncthreads();
  for (int d = 128; d > 0; d >>= 1) {
    if ((int)threadIdx.x < d) red[threadIdx.x] += red[threadIdx.x + d];
    __syncthreads();
  }
  if (threadIdx.x == 0) out[0] = red[0] * (1.0f / NR);
}

extern "C" void kernel_launch(void* const* d_in, const int* in_sizes, int n_in,
                              void* d_out, int out_size, void* d_ws, size_t ws_size,
                              hipStream_t stream) {
  const float* x = (const float*)d_in[0];
  const int* y = (const int*)d_in[1];
  const float* W = (const float*)d_in[2];
  float* out = (float*)d_out;
  char* ws = (char*)d_ws;

  if (ws_size >= NEED_NEW) {
    u8* x8      = (u8*)(ws + OFF_X8);
    u8* w8      = (u8*)(ws + OFF_W8);
    float* pmax = (float*)(ws + OFF_PMX);
    float* psum = (float*)(ws + OFF_PSM);
    float* lse  = (float*)(ws + OFF_LSE);
    float* tl   = (float*)(ws + OFF_TL);
    cvt_x8_kernel<<<NR * HD / 16 / 256, 256, 0, stream>>>(x, x8);
    cvt_w8_kernel<<<4096, 256, 0, stream>>>(W, w8);
    gemm8<<<NMB8 * NVB8, 1024, 0, stream>>>(x8, w8, pmax, psum);
    row_lse_kernel<<<NR / 64, 256, 0, stream>>>(pmax, psum, lse, NVB8);
    tlogit_kernel<<<NR / 4, 256, 0, stream>>>(x, y, W, tl);
    finalize_kernel<<<1, 256, 0, stream>>>(lse, tl, out);
  } else {
    u16* xb     = (u16*)(ws + FB_XB);
    float* pmax = (float*)(ws + FB_PMAX);
    float* psum = (float*)(ws + FB_PSUM);
    float* lse  = (float*)(ws + FB_LSE);
    float* tl   = (float*)(ws + FB_TL);
    cvt_x_kernel<<<NR * HD / 4 / 256, 256, 0, stream>>>(x, xb);
    gemm_partials_fb<<<NMBF * NVBF, 256, 0, stream>>>(xb, W, pmax, psum);
    row_lse_kernel<<<NR / 64, 256, 0, stream>>>(pmax, psum, lse, NVBF);
    tlogit_kernel<<<NR / 4, 256, 0, stream>>>(x, y, W, tl);
    finalize_kernel<<<1, 256, 0, stream>>>(lse, tl, out);
  }
}

// Round 10
// 2000.825 us; speedup vs baseline: 2.2228x; 2.2228x over previous
//
#include <hip/hip_runtime.h>
#include <hip/hip_fp8.h>

typedef unsigned short u16;
typedef unsigned char u8;
typedef unsigned int u32;
typedef long long i64;
typedef __attribute__((ext_vector_type(2))) i64 i64x2;
typedef __attribute__((ext_vector_type(8))) short short8;
typedef __attribute__((ext_vector_type(4))) float f32x4;

constexpr int HD = 2048;     // hidden / K (bytes in fp8)
constexpr int NR = 4096;     // rows B*S
constexpr int VO = 128000;   // vocab

// ---------------- fp8 path geometry: 256^2 tile, K-tile = 64 B ----------------
constexpr int NMB8 = NR / 256;    // 16
constexpr int NVB8 = VO / 256;    // 500
constexpr int NT8  = HD / 64;     // 32 K-tiles
constexpr float XSCALE = 32.0f;
constexpr float WSCALE = 16384.0f;
constexpr float UNSCALE = 1.0f / (XSCALE * WSCALE);

// ws layout (fp8 path)
constexpr size_t OFF_X8  = 0;                          // 8,388,608
constexpr size_t OFF_W8  = 8388608;                    // 262,144,000
constexpr size_t OFF_PMX = OFF_W8 + 262144000;         // 8,192,000
constexpr size_t OFF_PSM = OFF_PMX + 8192000;
constexpr size_t OFF_LSE = OFF_PSM + 8192000;
constexpr size_t OFF_TL  = OFF_LSE + 16384;
constexpr size_t NEED_NEW = OFF_TL + 16384;            // ~287 MB

// ws layout, fallback (round-1 bf16 128^2, proven)
constexpr int NVBF = VO / 128;
constexpr int NMBF = NR / 128;
constexpr size_t FB_XB   = 0;
constexpr size_t FB_PMAX = 16777216;
constexpr size_t FB_PSUM = FB_PMAX + 16384000;
constexpr size_t FB_LSE  = FB_PSUM + 16384000;
constexpr size_t FB_TL   = FB_LSE + (size_t)NR * 4;

// fallback swizzle
__device__ __forceinline__ u32 swz16(u32 a) { return a ^ (((a >> 7) & 3u) << 4); }

__device__ __forceinline__ u8 f2e4m3(float f) {
  return (u8)__hip_cvt_float_to_fp8(f, __HIP_SATFINITE, __HIP_E4M3);
}

// ---------------- x f32 -> fp8, kk-interleaved layout ----------------
// Per row, per 64B K-block: cell q (16B) holds elements k = kk*32 + q*8 + b
// at byte kk*8+b. One 16B LDS cell = a lane's full K=64 operand (both kk
// halves) -> single ds_read_b128 per fragment.
__global__ __launch_bounds__(256) void cvt_x8_kernel(const float* __restrict__ x,
                                                     u8* __restrict__ x8) {
  const long c = (long)blockIdx.x * 256 + threadIdx.x;   // 16B cell index
  const long row = c >> 7;                                // 128 cells/row
  const int ci = (int)(c & 127);
  const int tb = ci >> 2, q = ci & 3;
  const float* base = x + row * HD + tb * 64 + q * 8;
  float4 a0 = *reinterpret_cast<const float4*>(base);
  float4 a1 = *reinterpret_cast<const float4*>(base + 4);
  float4 a2 = *reinterpret_cast<const float4*>(base + 32);
  float4 a3 = *reinterpret_cast<const float4*>(base + 36);
  union { u8 b[16]; uint4 v; } p;
  p.b[0] = f2e4m3(a0.x * XSCALE); p.b[1] = f2e4m3(a0.y * XSCALE);
  p.b[2] = f2e4m3(a0.z * XSCALE); p.b[3] = f2e4m3(a0.w * XSCALE);
  p.b[4] = f2e4m3(a1.x * XSCALE); p.b[5] = f2e4m3(a1.y * XSCALE);
  p.b[6] = f2e4m3(a1.z * XSCALE); p.b[7] = f2e4m3(a1.w * XSCALE);
  p.b[8]  = f2e4m3(a2.x * XSCALE); p.b[9]  = f2e4m3(a2.y * XSCALE);
  p.b[10] = f2e4m3(a2.z * XSCALE); p.b[11] = f2e4m3(a2.w * XSCALE);
  p.b[12] = f2e4m3(a3.x * XSCALE); p.b[13] = f2e4m3(a3.y * XSCALE);
  p.b[14] = f2e4m3(a3.z * XSCALE); p.b[15] = f2e4m3(a3.w * XSCALE);
  reinterpret_cast<uint4*>(x8)[c] = p.v;
}

// ---------------- W f32 -> fp8, same kk-interleaved layout ----------------
__global__ __launch_bounds__(256) void cvt_w8_kernel(const float* __restrict__ W,
                                                     u8* __restrict__ w8) {
  const long total = (long)VO * HD / 16;                 // cells
  long c = (long)blockIdx.x * 256 + threadIdx.x;
  const long stride = (long)gridDim.x * 256;
  for (; c < total; c += stride) {
    const long row = c >> 7;
    const int ci = (int)(c & 127);
    const int tb = ci >> 2, q = ci & 3;
    const float* base = W + row * HD + tb * 64 + q * 8;
    float4 a0 = *reinterpret_cast<const float4*>(base);
    float4 a1 = *reinterpret_cast<const float4*>(base + 4);
    float4 a2 = *reinterpret_cast<const float4*>(base + 32);
    float4 a3 = *reinterpret_cast<const float4*>(base + 36);
    union { u8 b[16]; uint4 v; } p;
    p.b[0] = f2e4m3(a0.x * WSCALE); p.b[1] = f2e4m3(a0.y * WSCALE);
    p.b[2] = f2e4m3(a0.z * WSCALE); p.b[3] = f2e4m3(a0.w * WSCALE);
    p.b[4] = f2e4m3(a1.x * WSCALE); p.b[5] = f2e4m3(a1.y * WSCALE);
    p.b[6] = f2e4m3(a1.z * WSCALE); p.b[7] = f2e4m3(a1.w * WSCALE);
    p.b[8]  = f2e4m3(a2.x * WSCALE); p.b[9]  = f2e4m3(a2.y * WSCALE);
    p.b[10] = f2e4m3(a2.z * WSCALE); p.b[11] = f2e4m3(a2.w * WSCALE);
    p.b[12] = f2e4m3(a3.x * WSCALE); p.b[13] = f2e4m3(a3.y * WSCALE);
    p.b[14] = f2e4m3(a3.z * WSCALE); p.b[15] = f2e4m3(a3.w * WSCALE);
    reinterpret_cast<uint4*>(w8)[c] = p.v;
  }
}

// ============ 8-wave 256^2 fp8 fused GEMM + softmax partials ============
// 512 threads, wave tile 128x64 (acc[8][4] -> 128 AGPR), 256-reg class
// (__launch_bounds__(512,2)) so the REGISTER double-buffer (24 x i64x2 =
// 96 VGPR) fits WITHOUT spill (round-9 lesson: 1024,4 -> 128-cap -> 8.5GB
// scratch). Triple-buffered LDS (3 x 32KB). Body(T):
//   stage T+2 -> vmcnt(4)+BAR+sched_barrier -> ds_read frags(T+1) [12 x b128,
//   conflict-free slot-XOR layout] overlapping MFMA frags(T) -> lgkm0.
// Hazard: stage(T+2) targets buf((T+2)%3) whose last readers (frags T-1,
// read in body(T-2), retired by body(T-2)'s lgkm0) are separated from this
// stage by BAR(T-1). vmcnt: prologue stages {T0,T1}=8 loads; steady: stage
// T+2 then vmcnt(4) -> T+1 landed (outstanding T+1:4 + T+2:4 = 8).
__global__ __launch_bounds__(512, 2) void gemm8(
    const u8* __restrict__ x8, const u8* __restrict__ w8,
    float* __restrict__ pmax, float* __restrict__ psum) {
  __shared__ uint4 smem4[6144];                 // 96 KB: 3 bufs x {A 16K, B 16K}
  __shared__ float smax[256][4];
  __shared__ float ssum[256][4];
  char* Sm = reinterpret_cast<char*>(smem4);

  const int tid = threadIdx.x;
  const int w = tid >> 6, l = tid & 63;
  const int wr = w >> 2, wc = w & 3;            // 2M x 4N waves, 128x64 each
  const int q = l >> 4, r15 = l & 15;

  // XCD-bijective swizzle: 8000 = 8 * 1000; mb fast (W panel L2-reuse)
  const int bid = blockIdx.x;
  const int s = (bid & 7) * 1000 + (bid >> 3);
  const int mb = s & (NMB8 - 1);
  const int vb = s >> 4;
  const int rowbase = mb * 256, vbase = vb * 256;

  // -------- staging: 4 calls/tile (A rows 0-127, 128-255; B same) --------
  // call i: lin = i*8192 + tid*16; row = lin>>6; stored slot s_st=(lin>>4)&3
  // holds logical slot qsl = s_st ^ (row&3)  (slot-XOR, conflict-free reads).
  const u8* aS0; const u8* aS1; const u8* bS0; const u8* bS1;
  {
    u32 lin0 = (u32)tid * 16u;
    u32 r0 = lin0 >> 6, q0 = ((lin0 >> 4) & 3u) ^ (r0 & 3u);
    u32 lin1 = 8192u + (u32)tid * 16u;
    u32 r1 = lin1 >> 6, q1 = ((lin1 >> 4) & 3u) ^ (r1 & 3u);
    aS0 = x8 + (size_t)(rowbase + (int)r0) * HD + q0 * 16u;
    aS1 = x8 + (size_t)(rowbase + (int)r1) * HD + q1 * 16u;
    bS0 = w8 + (size_t)(vbase + (int)r0) * HD + q0 * 16u;
    bS1 = w8 + (size_t)(vbase + (int)r1) * HD + q1 * 16u;
  }
  const u32 dA0 = (u32)(w * 1024);
  const u32 dA1 = 8192u + (u32)(w * 1024);
  const u32 dB0 = 16384u + (u32)(w * 1024);
  const u32 dB1 = 24576u + (u32)(w * 1024);

  auto stg = [&](const u8* src, u32 dstOff) {
    __builtin_amdgcn_global_load_lds(
        (const __attribute__((address_space(1))) u32*)src,
        (__attribute__((address_space(3))) u32*)(Sm + dstOff), 16, 0, 0);
  };
#define STAGE(T, OFF) do {                      \
    stg(aS0 + (size_t)(T) * 64, (OFF) + dA0);   \
    stg(aS1 + (size_t)(T) * 64, (OFF) + dA1);   \
    stg(bS0 + (size_t)(T) * 64, (OFF) + dB0);   \
    stg(bS1 + (size_t)(T) * 64, (OFF) + dB1);   \
  } while (0)

  // -------- fragment read bases: one b128 per frag, slot = q^(r15&3) --------
  const u32 slot = ((u32)q ^ ((u32)r15 & 3u)) << 4;
  const u32 aBase = ((u32)(wr * 128 + r15) << 6) + slot;            // + jj*1024
  const u32 bBase = 16384u + ((u32)(wc * 64 + r15) << 6) + slot;    // + nn*1024

  i64x2 s0a[8], s0b[4], s1a[8], s1b[4];
  f32x4 acc[8][4];
#pragma unroll
  for (int m = 0; m < 8; ++m)
#pragma unroll
    for (int n = 0; n < 4; ++n) acc[m][n] = (f32x4)(0.0f);

#define RD_NEXT(NA, NB) do {                                                   \
    const char* _p = Sm + rdOff;                                               \
    _Pragma("unroll") for (int jj = 0; jj < 8; ++jj)                           \
      NA[jj] = *reinterpret_cast<const i64x2*>(_p + aBase + jj * 1024);        \
    _Pragma("unroll") for (int nn = 0; nn < 4; ++nn)                           \
      NB[nn] = *reinterpret_cast<const i64x2*>(_p + bBase + nn * 1024);        \
  } while (0)

#define MM(CA, CB) do {                                                        \
    __builtin_amdgcn_s_setprio(1);                                             \
    _Pragma("unroll") for (int jj = 0; jj < 8; ++jj)                           \
      _Pragma("unroll") for (int nn = 0; nn < 4; ++nn) {                       \
        acc[jj][nn] = __builtin_amdgcn_mfma_f32_16x16x32_fp8_fp8(              \
            CA[jj][0], CB[nn][0], acc[jj][nn], 0, 0, 0);                       \
        acc[jj][nn] = __builtin_amdgcn_mfma_f32_16x16x32_fp8_fp8(              \
            CA[jj][1], CB[nn][1], acc[jj][nn], 0, 0, 0);                       \
      }                                                                        \
    __builtin_amdgcn_s_setprio(0);                                             \
  } while (0)

#define BODY(T, CA, CB, NA, NB) do {                                           \
    if ((T) + 2 < NT8) { STAGE((T) + 2, stOff); }                              \
    if ((T) + 1 < NT8) {                                                       \
      if ((T) + 2 < NT8) asm volatile("s_waitcnt vmcnt(4)" ::: "memory");      \
      else               asm volatile("s_waitcnt vmcnt(0)" ::: "memory");      \
      __builtin_amdgcn_s_barrier();                                            \
      __builtin_amdgcn_sched_barrier(0);                                       \
      RD_NEXT(NA, NB);                                                         \
    }                                                                          \
    MM(CA, CB);                                                                \
    asm volatile("s_waitcnt lgkmcnt(0)" ::: "memory");                         \
    __builtin_amdgcn_sched_barrier(0);                                         \
    rdOff = (rdOff == 65536u) ? 0u : rdOff + 32768u;                           \
    stOff = (stOff == 65536u) ? 0u : stOff + 32768u;                           \
  } while (0)

  // -------- prologue: stage T0 -> buf0, T1 -> buf1; preload frags(T0) --------
  STAGE(0, 0u);
  STAGE(1, 32768u);
  asm volatile("s_waitcnt vmcnt(4)" ::: "memory");
  __builtin_amdgcn_s_barrier();
  __builtin_amdgcn_sched_barrier(0);
  {
    const char* _p = Sm;
#pragma unroll
    for (int jj = 0; jj < 8; ++jj)
      s0a[jj] = *reinterpret_cast<const i64x2*>(_p + aBase + jj * 1024);
#pragma unroll
    for (int nn = 0; nn < 4; ++nn)
      s0b[nn] = *reinterpret_cast<const i64x2*>(_p + bBase + nn * 1024);
  }
  u32 rdOff = 32768u;                           // body(0) reads T1 from buf1
  u32 stOff = 65536u;                           // body(0) stages T2 -> buf2

  // -------- K-loop: 32 tiles, unrolled x2 for static frag-set alternation ----
  for (int t = 0; t < NT8; t += 2) {
    BODY(t,     s0a, s0b, s1a, s1b);
    BODY(t + 1, s1a, s1b, s0a, s0b);
  }
#undef BODY
#undef MM
#undef RD_NEXT
#undef STAGE

  // -------- epilogue: unscale, per-row max + sum(exp) over 256 vocab cols ----
  // C/D: col = lane&15, row = (lane>>4)*4 + reg. Wave rows: wr*128+jj*16+q*4+j;
  // wave cols: wc*64 + nn*16 + (lane&15).
#pragma unroll
  for (int jj = 0; jj < 8; ++jj) {
#pragma unroll
    for (int j = 0; j < 4; ++j) {
      float v0 = acc[jj][0][j] * UNSCALE, v1 = acc[jj][1][j] * UNSCALE;
      float v2 = acc[jj][2][j] * UNSCALE, v3 = acc[jj][3][j] * UNSCALE;
      float mx = fmaxf(fmaxf(v0, v1), fmaxf(v2, v3));
#pragma unroll
      for (int d = 1; d < 16; d <<= 1) mx = fmaxf(mx, __shfl_xor(mx, d));
      float se = __expf(v0 - mx) + __expf(v1 - mx) + __expf(v2 - mx) + __expf(v3 - mx);
#pragma unroll
      for (int d = 1; d < 16; d <<= 1) se += __shfl_xor(se, d);
      if (r15 == 0) {
        int r = wr * 128 + jj * 16 + q * 4 + j;
        smax[r][wc] = mx;
        ssum[r][wc] = se;
      }
    }
  }
  __syncthreads();
  if (tid < 256) {
    float m0 = smax[tid][0], m1 = smax[tid][1], m2 = smax[tid][2], m3 = smax[tid][3];
    float M = fmaxf(fmaxf(m0, m1), fmaxf(m2, m3));
    float S = ssum[tid][0] * __expf(m0 - M) + ssum[tid][1] * __expf(m1 - M) +
              ssum[tid][2] * __expf(m2 - M) + ssum[tid][3] * __expf(m3 - M);
    size_t o = (size_t)vb * NR + (size_t)(rowbase + tid);
    pmax[o] = M;
    psum[o] = S;
  }
}

// ================= fallback path (round-1 bf16, proven) =================
__global__ __launch_bounds__(256) void cvt_x_kernel(const float* __restrict__ x,
                                                    u16* __restrict__ xb) {
  int i = blockIdx.x * 256 + threadIdx.x;
  float4 v = reinterpret_cast<const float4*>(x)[i];
  union { __bf16 b[4]; unsigned long long ll; } p;
  p.b[0] = (__bf16)v.x; p.b[1] = (__bf16)v.y;
  p.b[2] = (__bf16)v.z; p.b[3] = (__bf16)v.w;
  reinterpret_cast<unsigned long long*>(xb)[i] = p.ll;
}

__global__ __launch_bounds__(256) void gemm_partials_fb(
    const u16* __restrict__ xb, const float* __restrict__ W,
    float* __restrict__ pmax, float* __restrict__ psum) {
  __shared__ uint4 smem[1024];
  __shared__ float smax[128][2];
  __shared__ float ssum[128][2];
  char* Ab = reinterpret_cast<char*>(smem);
  char* Bb = Ab + 8192;

  const int tid = threadIdx.x;
  const int w = tid >> 6;
  const int l = tid & 63;
  const int wr = w >> 1, wc = w & 1;

  const int bid = blockIdx.x;
  const int s = (bid & 7) * (NMBF * NVBF / 8) + (bid >> 3);
  const int mb = s & (NMBF - 1);
  const int vb = s >> 5;
  const int rowbase = mb * 128;
  const int vbase = vb * 128;

  const u16* aSrc[2];
  unsigned aBase[2];
#pragma unroll
  for (int i = 0; i < 2; ++i) {
    unsigned lin = (unsigned)w * 2048u + (unsigned)i * 1024u + (unsigned)l * 16u;
    unsigned sb = swz16(lin);
    unsigned r = sb >> 6;
    unsigned c = (sb >> 1) & 31u;
    aSrc[i] = xb + (size_t)(rowbase + (int)r) * HD + c;
    aBase[i] = (unsigned)w * 2048u + (unsigned)i * 1024u;
  }
  const float* bSrc[2];
  unsigned bLin[2];
#pragma unroll
  for (int i = 0; i < 2; ++i) {
    unsigned lin = (unsigned)i * 4096u + (unsigned)tid * 16u;
    unsigned sb = swz16(lin);
    unsigned n = sb >> 6;
    unsigned k = (sb >> 1) & 31u;
    bSrc[i] = W + (size_t)(vbase + (int)n) * HD + k;
    bLin[i] = lin;
  }
  const unsigned q = (unsigned)(l >> 4);
  unsigned aOff[4], bOff[4];
#pragma unroll
  for (int m = 0; m < 4; ++m) {
    unsigned R = (unsigned)(wr * 64 + m * 16 + (l & 15));
    aOff[m] = swz16(R * 64u + q * 16u);
    R = (unsigned)(wc * 64 + m * 16 + (l & 15));
    bOff[m] = swz16(R * 64u + q * 16u);
  }
  f32x4 acc[4][4];
#pragma unroll
  for (int m = 0; m < 4; ++m)
#pragma unroll
    for (int n = 0; n < 4; ++n) acc[m][n] = (f32x4)(0.0f);

  for (int kt = 0; kt < HD; kt += 32) {
    float4 g0 = *reinterpret_cast<const float4*>(bSrc[0]);
    float4 g1 = *reinterpret_cast<const float4*>(bSrc[0] + 4);
    float4 g2 = *reinterpret_cast<const float4*>(bSrc[1]);
    float4 g3 = *reinterpret_cast<const float4*>(bSrc[1] + 4);
#pragma unroll
    for (int i = 0; i < 2; ++i) {
      __builtin_amdgcn_global_load_lds(
          (const __attribute__((address_space(1))) u32*)aSrc[i],
          (__attribute__((address_space(3))) u32*)(Ab + aBase[i]), 16, 0, 0);
    }
    union { __bf16 b[8]; uint4 v; } p0, p1;
    p0.b[0] = (__bf16)g0.x; p0.b[1] = (__bf16)g0.y; p0.b[2] = (__bf16)g0.z; p0.b[3] = (__bf16)g0.w;
    p0.b[4] = (__bf16)g1.x; p0.b[5] = (__bf16)g1.y; p0.b[6] = (__bf16)g1.z; p0.b[7] = (__bf16)g1.w;
    p1.b[0] = (__bf16)g2.x; p1.b[1] = (__bf16)g2.y; p1.b[2] = (__bf16)g2.z; p1.b[3] = (__bf16)g2.w;
    p1.b[4] = (__bf16)g3.x; p1.b[5] = (__bf16)g3.y; p1.b[6] = (__bf16)g3.z; p1.b[7] = (__bf16)g3.w;
    *reinterpret_cast<uint4*>(Bb + bLin[0]) = p0.v;
    *reinterpret_cast<uint4*>(Bb + bLin[1]) = p1.v;
    __syncthreads();

    short8 af[4], bfr[4];
#pragma unroll
    for (int m = 0; m < 4; ++m) af[m] = *reinterpret_cast<const short8*>(Ab + aOff[m]);
#pragma unroll
    for (int n = 0; n < 4; ++n) bfr[n] = *reinterpret_cast<const short8*>(Bb + bOff[n]);
#pragma unroll
    for (int m = 0; m < 4; ++m)
#pragma unroll
      for (int n = 0; n < 4; ++n)
        acc[m][n] = __builtin_amdgcn_mfma_f32_16x16x32_bf16(af[m], bfr[n], acc[m][n], 0, 0, 0);
    __syncthreads();

    aSrc[0] += 32; aSrc[1] += 32;
    bSrc[0] += 32; bSrc[1] += 32;
  }
#pragma unroll
  for (int m = 0; m < 4; ++m) {
#pragma unroll
    for (int j = 0; j < 4; ++j) {
      float v0 = acc[m][0][j], v1 = acc[m][1][j], v2 = acc[m][2][j], v3 = acc[m][3][j];
      float mx = fmaxf(fmaxf(v0, v1), fmaxf(v2, v3));
#pragma unroll
      for (int d = 1; d < 16; d <<= 1) mx = fmaxf(mx, __shfl_xor(mx, d));
      float se = __expf(v0 - mx) + __expf(v1 - mx) + __expf(v2 - mx) + __expf(v3 - mx);
#pragma unroll
      for (int d = 1; d < 16; d <<= 1) se += __shfl_xor(se, d);
      if ((l & 15) == 0) {
        int rloc = wr * 64 + m * 16 + (int)q * 4 + j;
        smax[rloc][wc] = mx;
        ssum[rloc][wc] = se;
      }
    }
  }
  __syncthreads();
  if (tid < 128) {
    float m0 = smax[tid][0], m1 = smax[tid][1];
    float M = fmaxf(m0, m1);
    float S = ssum[tid][0] * __expf(m0 - M) + ssum[tid][1] * __expf(m1 - M);
    size_t o = (size_t)vb * NR + (size_t)(rowbase + tid);
    pmax[o] = M;
    psum[o] = S;
  }
}

// ---------------- merge partials -> LSE per row ----------------
__global__ __launch_bounds__(256) void row_lse_kernel(const float* __restrict__ pmax,
                                                      const float* __restrict__ psum,
                                                      float* __restrict__ lse, int nvb) {
  __shared__ float lm[4][64];
  __shared__ float ls[4][64];
  const int rb = blockIdx.x * 64;
  const int rl = threadIdx.x & 63;
  const int g = threadIdx.x >> 6;
  const int r = rb + rl;
  float M = -3.0e38f, S = 0.0f;
  for (int v = g; v < nvb; v += 4) {
    float m = pmax[(size_t)v * NR + r];
    float s = psum[(size_t)v * NR + r];
    float nM = fmaxf(M, m);
    S = S * __expf(M - nM) + s * __expf(m - nM);
    M = nM;
  }
  lm[g][rl] = M; ls[g][rl] = S;
  __syncthreads();
  if (threadIdx.x < 64) {
    float M0 = lm[0][rl], S0 = ls[0][rl];
#pragma unroll
    for (int g2 = 1; g2 < 4; ++g2) {
      float m = lm[g2][rl], s2 = ls[g2][rl];
      float nM = fmaxf(M0, m);
      S0 = S0 * __expf(M0 - nM) + s2 * __expf(m - nM);
      M0 = nM;
    }
    lse[r] = M0 + logf(S0);
  }
}

// ---------------- target logit: dot(x[n], W[y[n]]) in f32 (exact) ----------------
__global__ __launch_bounds__(256) void tlogit_kernel(const float* __restrict__ x,
                                                     const int* __restrict__ y,
                                                     const float* __restrict__ W,
                                                     float* __restrict__ tl) {
  const int row = blockIdx.x * 4 + (threadIdx.x >> 6);
  const int l = threadIdx.x & 63;
  const int t = y[row];
  const float4* xr = reinterpret_cast<const float4*>(x + (size_t)row * HD);
  const float4* wr = reinterpret_cast<const float4*>(W + (size_t)t * HD);
  float s = 0.0f;
#pragma unroll
  for (int i = 0; i < HD / 4 / 64; ++i) {
    float4 a = xr[l + i * 64];
    float4 b = wr[l + i * 64];
    s += a.x * b.x + a.y * b.y + a.z * b.z + a.w * b.w;
  }
#pragma unroll
  for (int d = 1; d < 64; d <<= 1) s += __shfl_xor(s, d);
  if (l == 0) tl[row] = s;
}

// ---------------- mean(lse - tlogit) ----------------
__global__ __launch_bounds__(256) void finalize_kernel(const float* __restrict__ lse,
                                                       const float* __restrict__ tl,
                                                       float* __restrict__ out) {
  __shared__ float red[256];
  float s = 0.0f;
  for (int i = threadIdx.x; i < NR; i += 256) s += lse[i] - tl[i];
  red[threadIdx.x] = s;
  __syncthreads();
  for (int d = 128; d > 0; d >>= 1) {
    if ((int)threadIdx.x < d) red[threadIdx.x] += red[threadIdx.x + d];
    __syncthreads();
  }
  if (threadIdx.x == 0) out[0] = red[0] * (1.0f / NR);
}

extern "C" void kernel_launch(void* const* d_in, const int* in_sizes, int n_in,
                              void* d_out, int out_size, void* d_ws, size_t ws_size,
                              hipStream_t stream) {
  const float* x = (const float*)d_in[0];
  const int* y = (const int*)d_in[1];
  const float* W = (const float*)d_in[2];
  float* out = (float*)d_out;
  char* ws = (char*)d_ws;

  if (ws_size >= NEED_NEW) {
    u8* x8      = (u8*)(ws + OFF_X8);
    u8* w8      = (u8*)(ws + OFF_W8);
    float* pmax = (float*)(ws + OFF_PMX);
    float* psum = (float*)(ws + OFF_PSM);
    float* lse  = (float*)(ws + OFF_LSE);
    float* tl   = (float*)(ws + OFF_TL);
    cvt_x8_kernel<<<NR * HD / 16 / 256, 256, 0, stream>>>(x, x8);
    cvt_w8_kernel<<<4096, 256, 0, stream>>>(W, w8);
    gemm8<<<NMB8 * NVB8, 512, 0, stream>>>(x8, w8, pmax, psum);
    row_lse_kernel<<<NR / 64, 256, 0, stream>>>(pmax, psum, lse, NVB8);
    tlogit_kernel<<<NR / 4, 256, 0, stream>>>(x, y, W, tl);
    finalize_kernel<<<1, 256, 0, stream>>>(lse, tl, out);
  } else {
    u16* xb     = (u16*)(ws + FB_XB);
    float* pmax = (float*)(ws + FB_PMAX);
    float* psum = (float*)(ws + FB_PSUM);
    float* lse  = (float*)(ws + FB_LSE);
    float* tl   = (float*)(ws + FB_TL);
    cvt_x_kernel<<<NR * HD / 4 / 256, 256, 0, stream>>>(x, xb);
    gemm_partials_fb<<<NMBF * NVBF, 256, 0, stream>>>(xb, W, pmax, psum);
    row_lse_kernel<<<NR / 64, 256, 0, stream>>>(pmax, psum, lse, NVBF);
    tlogit_kernel<<<NR / 4, 256, 0, stream>>>(x, y, W, tl);
    finalize_kernel<<<1, 256, 0, stream>>>(lse, tl, out);
  }
}